// Round 1
// baseline (4118.007 us; speedup 1.0000x reference)
//
#include <hip/hip_runtime.h>
#include <hip/hip_bf16.h>
#include <math.h>

#define C_   1024
#define P_   2304      // 48*48
#define S4   331776    // 24^4
#define PQ_  576       // 24*24

// ---------------- K1a: partial sum of squares over channel chunks ----------
__global__ void k_sumsq_partial(const float* __restrict__ fA,
                                const float* __restrict__ fB,
                                float* __restrict__ part) {
  int pch = blockIdx.x;          // 0..8  (p chunk of 256)
  int cc  = blockIdx.y;          // 0..3  (c chunk of 256)
  int fbi = blockIdx.z;          // 0..15 (feat*8 + b)
  const float* src = ((fbi >> 3) ? fB : fA) + (size_t)(fbi & 7) * C_ * P_;
  int p = pch * 256 + threadIdx.x;
  int cbase = cc * 256;
  float s = 0.f;
  for (int c = 0; c < 256; ++c) {
    float v = src[(size_t)(cbase + c) * P_ + p];
    s = fmaf(v, v, s);
  }
  part[((size_t)fbi * 4 + cc) * P_ + p] = s;
}

// ---------------- K1b: finalize inverse norms ------------------------------
__global__ void k_invnorm(const float* __restrict__ part, float* __restrict__ inv) {
  int p   = blockIdx.x * 256 + threadIdx.x;
  int fbi = blockIdx.y;
  float s = 1e-6f;   // EPS_L2
  for (int cc = 0; cc < 4; ++cc) s += part[((size_t)fbi * 4 + cc) * P_ + p];
  inv[(size_t)fbi * P_ + p] = 1.0f / sqrtf(s);
}

// ---------------- K2: correlation GEMM + relu/normalize/4D-maxpool ---------
// 96x96 tile == (one h-pair x all w) x (one h2-pair x all w2): pools to 24x24.
__global__ __launch_bounds__(256) void k_corr_pool(
    const float* __restrict__ fA, const float* __restrict__ fB,
    const float* __restrict__ invn, float* __restrict__ pooled) {
  __shared__ float smem[96 * 97];          // epilogue tile; staging overlays it
  float* As = smem;                        // [16][96]
  float* Bs = smem + 16 * 96;              // [16][96]
  const int b  = blockIdx.y;
  const int ti = blockIdx.x / 24;
  const int tj = blockIdx.x % 24;
  const int p0 = ti * 96, q0 = tj * 96;
  const int t  = threadIdx.x;
  const int tx = t & 15, ty = t >> 4;
  const float* Ab = fA + (size_t)b * C_ * P_;
  const float* Bb = fB + (size_t)b * C_ * P_;

  float acc[6][6];
#pragma unroll
  for (int a = 0; a < 6; ++a)
#pragma unroll
    for (int c = 0; c < 6; ++c) acc[a][c] = 0.f;

  for (int kt = 0; kt < C_; kt += 16) {
    // stage A/B tiles: 1536 floats each as float4 (rows of 96 are /4)
#pragma unroll
    for (int e = 0; e < 2; ++e) {
      int idx4 = t * 4 + e * 1024;
      if (idx4 < 1536) {
        int r = idx4 / 96, c2 = idx4 % 96;
        *(float4*)&As[idx4] = *(const float4*)&Ab[(size_t)(kt + r) * P_ + p0 + c2];
        *(float4*)&Bs[idx4] = *(const float4*)&Bb[(size_t)(kt + r) * P_ + q0 + c2];
      }
    }
    __syncthreads();
#pragma unroll
    for (int kk = 0; kk < 16; ++kk) {
      const float* Ak = &As[kk * 96];
      const float* Bk = &Bs[kk * 96];
      float af[6], bf[6];
      *(float2*)&af[0] = *(const float2*)&Ak[2 * ty];
      *(float2*)&af[2] = *(const float2*)&Ak[2 * ty + 32];
      *(float2*)&af[4] = *(const float2*)&Ak[2 * ty + 64];
      *(float2*)&bf[0] = *(const float2*)&Bk[2 * tx];
      *(float2*)&bf[2] = *(const float2*)&Bk[2 * tx + 32];
      *(float2*)&bf[4] = *(const float2*)&Bk[2 * tx + 64];
#pragma unroll
      for (int a = 0; a < 6; ++a)
#pragma unroll
        for (int c = 0; c < 6; ++c)
          acc[a][c] = fmaf(af[a], bf[c], acc[a][c]);
    }
    __syncthreads();
  }

  // scale by inverse feature norms, park tile in LDS (padded stride 97)
  const int Pl[6] = {2*ty, 2*ty+1, 2*ty+32, 2*ty+33, 2*ty+64, 2*ty+65};
  const int Ql[6] = {2*tx, 2*tx+1, 2*tx+32, 2*tx+33, 2*tx+64, 2*tx+65};
  const float* invA = invn + (size_t)b * P_;
  const float* invB = invn + (size_t)(8 + b) * P_;
  float ia[6], ib[6];
#pragma unroll
  for (int a = 0; a < 6; ++a) ia[a] = invA[p0 + Pl[a]];
#pragma unroll
  for (int c = 0; c < 6; ++c) ib[c] = invB[q0 + Ql[c]];
#pragma unroll
  for (int a = 0; a < 6; ++a)
#pragma unroll
    for (int c = 0; c < 6; ++c)
      smem[Pl[a] * 97 + Ql[c]] = acc[a][c] * ia[a] * ib[c];
  __syncthreads();

  // 2x2x2x2 max pool, then relu + x/sqrt(x^2+eps) (monotone -> after max)
  for (int idx = t; idx < 576; idx += 256) {
    int j = idx / 24, l = idx % 24;
    float m = -1e30f;
#pragma unroll
    for (int dh = 0; dh < 2; ++dh)
#pragma unroll
      for (int dw = 0; dw < 2; ++dw) {
        int row = dh * 48 + 2 * j + dw;
#pragma unroll
        for (int d2 = 0; d2 < 2; ++d2)
#pragma unroll
          for (int dw2 = 0; dw2 < 2; ++dw2)
            m = fmaxf(m, smem[row * 97 + d2 * 48 + 2 * l + dw2]);
      }
    float r = fmaxf(m, 0.f);
    float v = r / sqrtf(r * r + 1e-6f);
    pooled[(size_t)b * S4 + (size_t)(ti * 24 + j) * 576 + tj * 24 + l] = v;
  }
}

// ---------------- K3a: row max (over kl, per ij) ---------------------------
__global__ void k_rowmax(const float* __restrict__ x, float* __restrict__ amax) {
  int row = blockIdx.x;                       // b*576 + ij
  const float* r = x + (size_t)row * 576;
  float m = -1e30f;
  for (int e = threadIdx.x; e < 576; e += 64) m = fmaxf(m, r[e]);
  for (int off = 32; off > 0; off >>= 1) m = fmaxf(m, __shfl_down(m, off, 64));
  if (threadIdx.x == 0) amax[row] = m;
}

// ---------------- K3b: col max (over ij, per kl) ---------------------------
__global__ void k_colmax(const float* __restrict__ x, float* __restrict__ bmax) {
  int b  = blockIdx.x;
  int kl = threadIdx.x;                       // 0..575
  const float* xb = x + (size_t)b * S4;
  float m = -1e30f;
  for (int ij = 0; ij < 576; ++ij) m = fmaxf(m, xb[(size_t)ij * 576 + kl]);
  bmax[b * 576 + kl] = m;
}

// ---------------- K4: mutual matching elementwise --------------------------
__global__ void k_mm_apply(const float* __restrict__ x,
                           const float* __restrict__ amax,
                           const float* __restrict__ bmax,
                           float* __restrict__ y) {
  int i = blockIdx.x * 256 + threadIdx.x;     // < 8*S4 = 2654208
  int b = i / S4, r = i % S4;
  int ij = r / 576, kl = r % 576;
  float c = x[i];
  y[i] = c * (c / (amax[b * 576 + ij] + 1e-5f)) * (c / (bmax[b * 576 + kl] + 1e-5f));
}

// ---------------- K5/6/7: direct 4D conv (3^4 taps, SAME) + ReLU -----------
// One block per (i,j); 576 threads over (k,l); per-(ci,di,dj) stage a 26x26
// zero-haloed (k,l) plane in LDS; weights read uniformly -> SGPR.
template <int CIN, int COUT>
__global__ void k_conv4d(const float* __restrict__ x, const float* __restrict__ w,
                         const float* __restrict__ bias, float* __restrict__ y) {
  __shared__ float plane[26 * 26];
  const int ij = blockIdx.x;
  const int i = ij / 24, j = ij % 24;
  const int t = threadIdx.x;                  // 0..575
  const int k = t / 24, l = t % 24;
  float acc[COUT];
#pragma unroll
  for (int co = 0; co < COUT; ++co) acc[co] = 0.f;

  for (int ci = 0; ci < CIN; ++ci) {
#pragma unroll
    for (int di = 0; di < 3; ++di) {
      int ii = i + di - 1;
      if (ii < 0 || ii >= 24) continue;       // uniform per block
#pragma unroll
      for (int dj = 0; dj < 3; ++dj) {
        int jj = j + dj - 1;
        if (jj < 0 || jj >= 24) continue;     // uniform per block
        const float* src = x + ((size_t)(ci * 24 + ii) * 24 + jj) * 576;
        __syncthreads();
        for (int e = t; e < 676; e += 576) {
          int a = e / 26, c2 = e % 26;
          int kk = a - 1, ll = c2 - 1;
          float v = 0.f;
          if (kk >= 0 && kk < 24 && ll >= 0 && ll < 24) v = src[kk * 24 + ll];
          plane[e] = v;
        }
        __syncthreads();
        float tap[9];
#pragma unroll
        for (int dk = 0; dk < 3; ++dk)
#pragma unroll
          for (int dl = 0; dl < 3; ++dl)
            tap[dk * 3 + dl] = plane[(k + dk) * 26 + (l + dl)];
        const float* wp = w + ((ci * 3 + di) * 3 + dj) * 9;
#pragma unroll
        for (int co = 0; co < COUT; ++co)
#pragma unroll
          for (int tt = 0; tt < 9; ++tt)
            acc[co] = fmaf(tap[tt], wp[(size_t)co * CIN * 81 + tt], acc[co]);
      }
    }
  }
#pragma unroll
  for (int co = 0; co < COUT; ++co) {
    float v = fmaxf(acc[co] + bias[co], 0.f);
    y[(size_t)co * S4 + (size_t)ij * 576 + t] = v;
  }
}

// ---------------------------------------------------------------------------
extern "C" void kernel_launch(void* const* d_in, const int* in_sizes, int n_in,
                              void* d_out, int out_size, void* d_ws, size_t ws_size,
                              hipStream_t stream) {
  const float* fA = (const float*)d_in[0];
  const float* fB = (const float*)d_in[1];
  const float* w1 = (const float*)d_in[2];
  const float* b1 = (const float*)d_in[3];
  const float* w2 = (const float*)d_in[4];
  const float* b2 = (const float*)d_in[5];
  const float* w3 = (const float*)d_in[6];
  const float* b3 = (const float*)d_in[7];
  float* out = (float*)d_out;

  float* ws = (float*)d_ws;
  size_t off = 0;
  auto alloc = [&](size_t n) {
    float* p = ws + off;
    off += (n + 63) & ~(size_t)63;
    return p;
  };
  float* part   = alloc((size_t)16 * 4 * P_);   // 147456
  float* invn   = alloc((size_t)16 * P_);       // 36864
  float* pooled = alloc((size_t)8 * S4);        // 2654208
  float* amax1  = alloc(8 * 576);
  float* bmax1  = alloc(8 * 576);
  float* C1b    = alloc((size_t)10 * S4);       // per-batch conv1 out
  float* C2b    = alloc((size_t)10 * S4);       // per-batch conv2 out
  float* C3     = alloc((size_t)8 * S4);        // conv3 out, all batches
  float* amax2  = alloc(8 * 576);
  float* bmax2  = alloc(8 * 576);
  (void)in_sizes; (void)n_in; (void)out_size; (void)ws_size;

  // 1) feature L2 norms (folded into GEMM as row/col scaling)
  k_sumsq_partial<<<dim3(9, 4, 16), 256, 0, stream>>>(fA, fB, part);
  k_invnorm<<<dim3(9, 16), 256, 0, stream>>>(part, invn);

  // 2) correlation + relu + normalize + 4D maxpool (fused)
  k_corr_pool<<<dim3(576, 8), 256, 0, stream>>>(fA, fB, invn, pooled);

  // 3) mutual matching #1 (in place)
  k_rowmax<<<dim3(8 * 576), 64, 0, stream>>>(pooled, amax1);
  k_colmax<<<dim3(8), 576, 0, stream>>>(pooled, bmax1);
  k_mm_apply<<<dim3(10368), 256, 0, stream>>>(pooled, amax1, bmax1, pooled);

  // 4) neighbourhood consensus: 3x conv4d + relu, per batch (small ws bufs)
  for (int b = 0; b < 8; ++b) {
    k_conv4d<1, 10><<<dim3(576), 576, 0, stream>>>(pooled + (size_t)b * S4, w1, b1, C1b);
    k_conv4d<10, 10><<<dim3(576), 576, 0, stream>>>(C1b, w2, b2, C2b);
    k_conv4d<10, 1><<<dim3(576), 576, 0, stream>>>(C2b, w3, b3, C3 + (size_t)b * S4);
  }

  // 5) mutual matching #2 -> final output
  k_rowmax<<<dim3(8 * 576), 64, 0, stream>>>(C3, amax2);
  k_colmax<<<dim3(8), 576, 0, stream>>>(C3, bmax2);
  k_mm_apply<<<dim3(10368), 256, 0, stream>>>(C3, amax2, bmax2, out);
}